// Round 14
// baseline (135.047 us; speedup 1.0000x reference)
//
#include <hip/hip_runtime.h>
#include <hip/hip_bf16.h>

typedef __bf16 bf16_t;
typedef __bf16 bf16x8 __attribute__((ext_vector_type(8)));
typedef __bf16 bf16x4 __attribute__((ext_vector_type(4)));
typedef float  f32x4  __attribute__((ext_vector_type(4)));
typedef float  f32x16 __attribute__((ext_vector_type(16)));
typedef unsigned int u32;
typedef unsigned int u32x2v __attribute__((ext_vector_type(2)));
typedef unsigned int u32x4v __attribute__((ext_vector_type(4)));

#define D_MODEL   1024
#define NQKV      3072
#define NQK       2048     // packed Q|K row stride (V lives only in Vt)
#define NUM_HEADS 16
#define HEAD_DIM  64
#define SEQ       2048
#define BATCH     2
#define NTOK      4096
#define SM_SCALE_LOG2E 0.18033688011112042f
#define LOG2_THETA 13.287712379549449f
#define NEG_BIG  (-3.0e38f)

// XOR slot swizzle for LDS tiles with 128-byte rows
__device__ __forceinline__ int swz128(int row, int bytecol) {
  return row*128 + ((((bytecol>>4) ^ (row&7))<<4) | (bytecol & 15));
}

__device__ __forceinline__ void gload16(const void* g, void* l) {
  __builtin_amdgcn_global_load_lds((const __attribute__((address_space(1))) u32*)g,
                                   (__attribute__((address_space(3))) u32*)l, 16, 0, 0);
}

__device__ __forceinline__ u32 cvtpk_bf16(float a, float b) {
  u32 r;
  asm("v_cvt_pk_bf16_f32 %0, %1, %2" : "=v"(r) : "v"(a), "v"(b));
  return r;
}

__device__ __forceinline__ void plswap(u32 &a, u32 &b) {
#if __has_builtin(__builtin_amdgcn_permlane32_swap)
  u32x2v r = __builtin_amdgcn_permlane32_swap(a, b, false, false);
  a = r[0]; b = r[1];
#else
  u32 xa = __shfl_xor((unsigned)a, 32, 64);
  u32 xb = __shfl_xor((unsigned)b, 32, 64);
  bool hi = (threadIdx.x & 32) != 0;
  a = hi ? xb : a;
  b = hi ? b : xa;
#endif
}

// 144 slots/bh: s<16 -> full q-wave s; 16<=s<80 -> halves of qw 16..47;
// s>=80 -> quarters of qw 48..63. Ordered by descending slice length.
__device__ const unsigned char slot_order144[144] = {
  72,74,76,77,78,79,
  64,66,68,69,70,71,73,75,
  56,58,60,61,62,63,65,67,
  48,50,52,53,54,55,57,59,
  14,15,40,42,44,45,46,47,49,51,115,119,121,123,125,127,129,130,131,133,
  134,135,136,137,138,139,140,141,142,143,
  12,13,32,34,36,37,38,39,41,43,83,87,89,91,93,95,97,98,99,101,
  102,103,104,105,106,107,108,109,110,111,112,113,114,116,117,118,120,122,124,126,
  128,132,
  10,11,24,26,28,29,30,31,33,35,80,81,82,84,85,86,88,90,92,94,96,100,
  8,9,16,18,20,21,22,23,25,27,
  6,7,17,19,
  4,5, 2,3, 0,1
};

// ---------------- fp32 -> bf16 conversion, single kernel ----------------
__global__ void cvt_all(const float* __restrict__ x,  const float* __restrict__ wq,
                        const float* __restrict__ wk, const float* __restrict__ wv,
                        const float* __restrict__ wo,
                        bf16_t* __restrict__ xb, bf16_t* __restrict__ wqkv,
                        bf16_t* __restrict__ wob) {
  const int NX = NTOK*D_MODEL;
  const int NW = D_MODEL*D_MODEL;
  int i = (blockIdx.x*256 + threadIdx.x)*4;
  float4 v; bf16_t* dst;
  if (i < NX) { v = *reinterpret_cast<const float4*>(x + i); dst = xb + i; }
  else {
    int k = i - NX;
    if      (k <   NW) { v = *reinterpret_cast<const float4*>(wq + k);        dst = wqkv + k; }
    else if (k < 2*NW) { v = *reinterpret_cast<const float4*>(wk + k -   NW); dst = wqkv + k; }
    else if (k < 3*NW) { v = *reinterpret_cast<const float4*>(wv + k - 2*NW); dst = wqkv + k; }
    else               { v = *reinterpret_cast<const float4*>(wo + k - 3*NW); dst = wob + k - 3*NW; }
  }
  bf16x4 o; o[0]=(bf16_t)v.x; o[1]=(bf16_t)v.y; o[2]=(bf16_t)v.z; o[3]=(bf16_t)v.w;
  *reinterpret_cast<bf16x4*>(dst) = o;
}

// ---------------- GEMM: C[M,N]=A[M,K]*B[N,K]^T — 4-slot counted-vmcnt -------
// If QKV: Q,K columns (n<2048) written at row stride NQK=2048 with fused RoPE;
// V columns written transposed to Vt only.
template<typename OutT, bool QKV>
__global__ __launch_bounds__(256, 1) void gemm8(const bf16_t* __restrict__ A,
                                                const bf16_t* __restrict__ B,
                                                OutT* __restrict__ C,
                                                bf16_t* __restrict__ Vt,
                                                const int* __restrict__ pos,
                                                int M, int N, int K) {
  __shared__ __align__(16) char lds[4][32768];
  int tid = threadIdx.x;
  int n0 = blockIdx.x*128, m0 = blockIdx.y*128;
  int wid = tid>>6, lane = tid&63;
  int wr = wid>>1, wc = wid&1;
  int lr = lane&15, lg = lane>>4;

  const int nT = K >> 6;
  const int CN = QKV ? NQK : N;

  int srow = tid >> 3;
  int sc8  = (tid & 7) ^ (srow & 7);
  const bf16_t* ga = A + (size_t)(m0 + srow)*K + sc8*8;
  const bf16_t* gb = B + (size_t)(n0 + srow)*K + sc8*8;

  f32x4 acc[4][4];
  #pragma unroll
  for (int a=0;a<4;a++)
    #pragma unroll
    for (int b=0;b<4;b++) acc[a][b] = (f32x4){0.f,0.f,0.f,0.f};

  auto stage = [&](int t) {
    char* s = lds[t&3];
    int k0 = t << 6;
    #pragma unroll
    for (int g=0; g<4; g++)
      gload16(ga + (size_t)(g*32)*K + k0, s + g*4096 + tid*16);
    #pragma unroll
    for (int g=0; g<4; g++)
      gload16(gb + (size_t)(g*32)*K + k0, s + 16384 + g*4096 + tid*16);
  };

  stage(0);
  if (nT > 1) stage(1);
  asm volatile("s_waitcnt vmcnt(8)" ::: "memory");
  __builtin_amdgcn_sched_barrier(0);
  __builtin_amdgcn_s_barrier();

  for (int t = 0; t < nT; ++t) {
    char* sA = lds[t&3];
    char* sB = sA + 16384;

    bf16x8 bq[4][2], aq[2][2];
    #pragma unroll
    for (int ni=0; ni<4; ni++)
      #pragma unroll
      for (int ks=0; ks<2; ks++)
        bq[ni][ks] = *reinterpret_cast<const bf16x8*>(sB + swz128(wc*64+ni*16+lr, ks*64+lg*16));
    #pragma unroll
    for (int mi=0; mi<2; mi++)
      #pragma unroll
      for (int ks=0; ks<2; ks++)
        aq[mi][ks] = *reinterpret_cast<const bf16x8*>(sA + swz128(wr*64+mi*16+lr, ks*64+lg*16));
    if (t + 2 < nT) stage(t + 2);
    asm volatile("s_waitcnt lgkmcnt(0)" ::: "memory");
    __builtin_amdgcn_sched_barrier(0);
    __builtin_amdgcn_s_setprio(1);
    #pragma unroll
    for (int mi=0; mi<2; mi++)
      #pragma unroll
      for (int ni=0; ni<4; ni++)
        #pragma unroll
        for (int ks=0; ks<2; ks++)
          acc[mi][ni] = __builtin_amdgcn_mfma_f32_16x16x32_bf16(aq[mi][ks], bq[ni][ks], acc[mi][ni], 0, 0, 0);
    __builtin_amdgcn_s_setprio(0);
    __builtin_amdgcn_s_barrier();

    bf16x8 aq2[2][2];
    #pragma unroll
    for (int mi=0; mi<2; mi++)
      #pragma unroll
      for (int ks=0; ks<2; ks++)
        aq2[mi][ks] = *reinterpret_cast<const bf16x8*>(sA + swz128(wr*64+(mi+2)*16+lr, ks*64+lg*16));
    asm volatile("s_waitcnt lgkmcnt(0)" ::: "memory");
    __builtin_amdgcn_sched_barrier(0);
    __builtin_amdgcn_s_setprio(1);
    #pragma unroll
    for (int mi=0; mi<2; mi++)
      #pragma unroll
      for (int ni=0; ni<4; ni++)
        #pragma unroll
        for (int ks=0; ks<2; ks++)
          acc[mi+2][ni] = __builtin_amdgcn_mfma_f32_16x16x32_bf16(aq2[mi][ks], bq[ni][ks], acc[mi+2][ni], 0, 0, 0);
    __builtin_amdgcn_s_setprio(0);
    if (t + 2 < nT)      { asm volatile("s_waitcnt vmcnt(8)" ::: "memory"); }
    else if (t + 1 < nT) { asm volatile("s_waitcnt vmcnt(0)" ::: "memory"); }
    __builtin_amdgcn_sched_barrier(0);
    __builtin_amdgcn_s_barrier();
  }

  if (QKV && n0 < 2*D_MODEL) {
    bool isQ = (n0 < D_MODEL);
    float fr[4];
    #pragma unroll
    for (int ni=0; ni<4; ni++) {
      int j = ((wc*64 + ni*16 + lr) & 63) >> 1;
      fr[ni] = exp2f(-(float)j * (LOG2_THETA/32.0f));
    }
    #pragma unroll
    for (int mi=0; mi<4; mi++)
      #pragma unroll
      for (int r=0; r<4; r++) {
        int m = m0 + wr*64 + mi*16 + lg*4 + r;
        float pt = (float)pos[m & (SEQ-1)];
        #pragma unroll
        for (int ni=0; ni<4; ni++) {
          int n = n0 + wc*64 + ni*16 + lr;
          float v = acc[mi][ni][r];
          float p = __shfl_xor(v, 1, 64);
          float sv, cv;
          __sincosf(pt * fr[ni], &sv, &cv);
          float o = (n & 1) ? (p*sv + v*cv) : (v*cv - p*sv);
          if (isQ) o *= SM_SCALE_LOG2E;
          C[(size_t)m*CN + n] = (OutT)o;
        }
      }
  } else if (!QKV) {
    #pragma unroll
    for (int mi=0;mi<4;mi++)
      #pragma unroll
      for (int ni=0;ni<4;ni++)
        #pragma unroll
        for (int r=0;r<4;r++) {
          int m = m0 + wr*64 + mi*16 + lg*4 + r;
          int n = n0 + wc*64 + ni*16 + lr;
          C[(size_t)m*CN + n] = (OutT)acc[mi][ni][r];
        }
  } else {
    #pragma unroll
    for (int mi=0;mi<4;mi++)
      #pragma unroll
      for (int ni=0;ni<4;ni++)
        #pragma unroll
        for (int r=0;r<4;r++) {
          int m = m0 + wr*64 + mi*16 + lg*4 + r;
          int nl = n0 + wc*64 + ni*16 + lr - 2*D_MODEL;
          int h = nl >> 6, d = nl & 63;
          int bb = m >> 11, s = m & (SEQ-1);
          Vt[(((size_t)(bb*16 + h)*64 + d) << 11) + s] = (bf16_t)acc[mi][ni][r];
        }
  }
}

// ---------------- Flash causal attention: 1-wave, 144-slot, T13 -------------
// grid (32 bh, 144 slots). LDS 16 KB (K 8 + V 8), per-iter full restage,
// no barriers. Partials: region A (slots s<112) / region B (s>=112), s-major.
__global__ __launch_bounds__(64, 2) void attn14(const bf16_t* __restrict__ QK,
                                                const bf16_t* __restrict__ Vt,
                                                bf16_t* __restrict__ pOA,
                                                bf16_t* __restrict__ pOB,
                                                float2* __restrict__ pML) {
  __shared__ __align__(16) char sK[64*128];
  __shared__ __align__(16) char sV[64*128];

  int bh = blockIdx.x;
  int b = bh >> 4, h = bh & 15;
  int lane = threadIdx.x & 63;
  int q32 = lane & 31, hi = lane >> 5;
  int rsub = lane >> 3, sg = (lane & 7) ^ rsub;

  int s = slot_order144[blockIdx.y];
  int qw, t0, t1;
  if (s < 16) { qw = s; t0 = 0; t1 = (s >> 1) + 1; }
  else if (s < 80) {
    int e = s - 16;
    qw = 16 + (e >> 1);
    int nt = (qw >> 1) + 1, h0 = (nt + 1) >> 1;
    t0 = (e & 1) ? h0 : 0;
    t1 = (e & 1) ? nt : h0;
  } else {
    int e = s - 80;
    qw = 48 + (e >> 2);
    int nt = (qw >> 1) + 1, qq = e & 3;
    t0 = (nt * qq) >> 2;
    t1 = (nt * (qq + 1)) >> 2;
  }
  int qt = qw >> 1;
  int qg = qw*32 + q32;

  bf16x8 qf[4];
  const bf16_t* qrow = QK + (size_t)(b*SEQ + qw*32 + q32)*NQK + h*64 + hi*8;
  #pragma unroll
  for (int d=0; d<4; d++) qf[d] = *reinterpret_cast<const bf16x8*>(qrow + d*16);

  const bf16_t* kgb = QK + D_MODEL + ((size_t)(b*SEQ) + rsub)*NQK + h*64 + sg*8;
  const bf16_t* vgb = Vt + (size_t)bh*64*SEQ + (size_t)rsub*SEQ + sg*8;

  auto stageK = [&](int t) {
    const bf16_t* src = kgb + (size_t)t*64*NQK;
    #pragma unroll
    for (int c=0;c<8;c++)
      gload16(src + (size_t)(8*c)*NQK, sK + c*1024 + lane*16);
  };
  auto stageV = [&](int t) {
    const bf16_t* src = vgb + t*64;
    #pragma unroll
    for (int c=0;c<8;c++)
      gload16(src + (size_t)(8*c)*SEQ, sV + c*1024 + lane*16);
  };

  f32x16 O0 = (f32x16)0.0f, O1 = (f32x16)0.0f;
  float mrun = NEG_BIG, lrun = 0.f;

  stageK(t0); stageV(t0);
  asm volatile("s_waitcnt vmcnt(0)" ::: "memory");
  __builtin_amdgcn_sched_barrier(0);

  for (int ti = t0; ti < t1; ++ti) {
    bf16x8 k0f[4], k1f[4], v0f[4], v1f[4];
    #pragma unroll
    for (int ds=0; ds<4; ds++) {
      k0f[ds] = *reinterpret_cast<const bf16x8*>(sK + swz128(q32,    ds*32 + hi*16));
      k1f[ds] = *reinterpret_cast<const bf16x8*>(sK + swz128(32+q32, ds*32 + hi*16));
      v0f[ds] = *reinterpret_cast<const bf16x8*>(sV + swz128(q32,    ds*32 + hi*16));
      v1f[ds] = *reinterpret_cast<const bf16x8*>(sV + swz128(32+q32, ds*32 + hi*16));
    }
    asm volatile("s_waitcnt lgkmcnt(0)" ::: "memory");
    __builtin_amdgcn_sched_barrier(0);
    if (ti + 1 < t1) { stageK(ti + 1); stageV(ti + 1); }

    f32x16 p0 = (f32x16)0.0f, p1 = (f32x16)0.0f;
    __builtin_amdgcn_s_setprio(1);
    #pragma unroll
    for (int ds=0; ds<4; ds++) {
      p0 = __builtin_amdgcn_mfma_f32_32x32x16_bf16(k0f[ds], qf[ds], p0, 0, 0, 0);
      p1 = __builtin_amdgcn_mfma_f32_32x32x16_bf16(k1f[ds], qf[ds], p1, 0, 0, 0);
    }
    __builtin_amdgcn_s_setprio(0);

    if (ti == qt) {
      #pragma unroll
      for (int r=0; r<16; r++) {
        int kg = ti*64 + (r&3) + 8*(r>>2) + 4*hi;
        if (kg      > qg) p0[r] = NEG_BIG;
        if (kg + 32 > qg) p1[r] = NEG_BIG;
      }
    }

    float mx[8];
    #pragma unroll
    for (int r=0;r<8;r++) mx[r] = fmaxf(fmaxf(p0[r],p0[r+8]), fmaxf(p1[r],p1[r+8]));
    #pragma unroll
    for (int st=4; st>0; st>>=1)
      #pragma unroll
      for (int r=0;r<st;r++) mx[r] = fmaxf(mx[r], mx[r+st]);
    float mt = fmaxf(mx[0], __shfl_xor(mx[0], 32, 64));

    // T13 defer-max: rescale only when the running max grew by > 8
    if (!__all(mt <= mrun + 8.0f)) {
      float mnew  = fmaxf(mrun, mt);
      float alpha = exp2f(mrun - mnew);
      lrun *= alpha;
      O0 *= alpha; O1 *= alpha;
      mrun = mnew;
    }
    #pragma unroll
    for (int r=0; r<16; r++) {
      p0[r] = exp2f(p0[r] - mrun);
      p1[r] = exp2f(p1[r] - mrun);
    }
    float sx[8];
    #pragma unroll
    for (int r=0;r<8;r++) sx[r] = (p0[r]+p0[r+8]) + (p1[r]+p1[r+8]);
    #pragma unroll
    for (int st=4; st>0; st>>=1)
      #pragma unroll
      for (int r=0;r<st;r++) sx[r] += sx[r+st];
    lrun += sx[0] + __shfl_xor(sx[0], 32, 64);

    u32 pk0[8], pk1[8];
    #pragma unroll
    for (int i2=0; i2<8; i2++) {
      pk0[i2] = cvtpk_bf16(p0[2*i2], p0[2*i2+1]);
      pk1[i2] = cvtpk_bf16(p1[2*i2], p1[2*i2+1]);
    }
    plswap(pk0[0], pk0[2]); plswap(pk0[1], pk0[3]);
    plswap(pk0[4], pk0[6]); plswap(pk0[5], pk0[7]);
    plswap(pk1[0], pk1[2]); plswap(pk1[1], pk1[3]);
    plswap(pk1[4], pk1[6]); plswap(pk1[5], pk1[7]);

    bf16x8 pa[4];
    pa[0] = __builtin_bit_cast(bf16x8, (u32x4v){pk0[0],pk0[1],pk0[2],pk0[3]});
    pa[1] = __builtin_bit_cast(bf16x8, (u32x4v){pk0[4],pk0[5],pk0[6],pk0[7]});
    pa[2] = __builtin_bit_cast(bf16x8, (u32x4v){pk1[0],pk1[1],pk1[2],pk1[3]});
    pa[3] = __builtin_bit_cast(bf16x8, (u32x4v){pk1[4],pk1[5],pk1[6],pk1[7]});

    __builtin_amdgcn_s_setprio(1);
    #pragma unroll
    for (int ks=0; ks<4; ks++) {
      O0 = __builtin_amdgcn_mfma_f32_32x32x16_bf16(v0f[ks], pa[ks], O0, 0, 0, 0);
      O1 = __builtin_amdgcn_mfma_f32_32x32x16_bf16(v1f[ks], pa[ks], O1, 0, 0, 0);
    }
    __builtin_amdgcn_s_setprio(0);

    if (ti + 1 < t1) {
      asm volatile("s_waitcnt vmcnt(0)" ::: "memory");
      __builtin_amdgcn_sched_barrier(0);
    }
  }

  bf16_t* base = (s < 112) ? (pOA + (size_t)(s*32 + bh)*2048)
                           : (pOB + (size_t)((s-112)*32 + bh)*2048);
  bf16_t* prow = base + q32*64;
  #pragma unroll
  for (int rg=0; rg<4; rg++) {
    int d0 = 8*rg + 4*hi;
    u32 a0 = cvtpk_bf16(O0[4*rg],   O0[4*rg+1]);
    u32 a1 = cvtpk_bf16(O0[4*rg+2], O0[4*rg+3]);
    *reinterpret_cast<u32x2v*>(prow + d0) = (u32x2v){a0, a1};
    u32 b0 = cvtpk_bf16(O1[4*rg],   O1[4*rg+1]);
    u32 b1 = cvtpk_bf16(O1[4*rg+2], O1[4*rg+3]);
    *reinterpret_cast<u32x2v*>(prow + 32 + d0) = (u32x2v){b0, b1};
  }
  if (hi == 0)
    pML[(s*32 + bh)*32 + q32] = make_float2(mrun, lrun);
}

// ---------------- combine partials -> Of (1/2/4-way) ----------------
__global__ __launch_bounds__(128) void combine(const bf16_t* __restrict__ pOA,
                                               const bf16_t* __restrict__ pOB,
                                               const float2* __restrict__ pML,
                                               bf16_t* __restrict__ Of) {
  int qw = blockIdx.x, bh = blockIdx.y;
  int b = bh >> 4, h = bh & 15;
  int t = threadIdx.x;
  int q = t >> 2, d0 = (t & 3) * 16;

  auto slotp = [&](int s) -> const bf16x8* {
    const bf16_t* base = (s < 112) ? (pOA + (size_t)(s*32 + bh)*2048)
                                   : (pOB + (size_t)((s-112)*32 + bh)*2048);
    return reinterpret_cast<const bf16x8*>(base + q*64 + d0);
  };
  auto mlv = [&](int s) -> float2 { return pML[(s*32 + bh)*32 + q]; };

  float r0[8], r1[8];
  #pragma unroll
  for (int i=0;i<8;i++) { r0[i]=0.f; r1[i]=0.f; }

  int s0, np;
  if (qw < 16)      { s0 = qw;               np = 1; }
  else if (qw < 48) { s0 = 16 + (qw-16)*2;   np = 2; }
  else              { s0 = 80 + (qw-48)*4;   np = 4; }

  float m = NEG_BIG;
  float2 ml[4];
  for (int i=0;i<np;i++) { ml[i] = mlv(s0+i); m = fmaxf(m, ml[i].x); }
  float lsum = 0.f, w[4];
  for (int i=0;i<np;i++) { w[i] = exp2f(ml[i].x - m); lsum += w[i]*ml[i].y; }
  float inv = 1.0f / lsum;

  for (int i=0;i<np;i++) {
    const bf16x8* sp = slotp(s0+i);
    bf16x8 o0 = sp[0], o1 = sp[1];
    float wi = w[i]*inv;
    #pragma unroll
    for (int j=0;j<8;j++) {
      r0[j] += wi*(float)o0[j];
      r1[j] += wi*(float)o1[j];
    }
  }

  bf16x8 y0, y1;
  #pragma unroll
  for (int j=0;j<8;j++) { y0[j]=(bf16_t)r0[j]; y1[j]=(bf16_t)r1[j]; }
  bf16x8* dst = reinterpret_cast<bf16x8*>(Of + ((size_t)(b*SEQ) + qw*32 + q)*D_MODEL + h*64 + d0);
  dst[0] = y0; dst[1] = y1;
}

// ---------------- launch ----------------
// Workspace lifetimes (48 MB):
//   [ 0, 14) pOA (attn/combine)   | earlier: xb [0,8) + wqkv [8,14)
//   [14, 16) wob  (persistent)
//   [16, 32) QK packed (gemm->attn) -> Of [16,24) (combine->out-gemm)
//   [32, 36) pOB, [36, 37.2) pML  (attn/combine)
//   [40, 48) Vtb  (gemm->attn)
extern "C" void kernel_launch(void* const* d_in, const int* in_sizes, int n_in,
                              void* d_out, int out_size, void* d_ws, size_t ws_size,
                              hipStream_t stream) {
  const float* x   = (const float*)d_in[0];
  const int*   pos = (const int*)  d_in[1];
  const float* wq  = (const float*)d_in[2];
  const float* wk  = (const float*)d_in[3];
  const float* wv  = (const float*)d_in[4];
  const float* wo  = (const float*)d_in[5];
  float* out = (float*)d_out;

  char* ws = (char*)d_ws;
  bf16_t* xb   = (bf16_t*)(ws);
  bf16_t* wqkv = (bf16_t*)(ws + ( 8u<<20));
  bf16_t* wob  = (bf16_t*)(ws + (14u<<20));
  bf16_t* QK   = (bf16_t*)(ws + (16u<<20));     // 16 MB packed Q|K
  bf16_t* Vtb  = (bf16_t*)(ws + (40u<<20));     // 8 MB
  bf16_t* pOA  = (bf16_t*)(ws);                 // 14 MB (3584 slots)
  bf16_t* pOB  = (bf16_t*)(ws + (32u<<20));     // 4 MB (1024 slots)
  float2* pML  = (float2*)(ws + (36u<<20));     // 1.18 MB
  bf16_t* Of   = (bf16_t*)(ws + (16u<<20));     // overlays dead QK

  cvt_all<<<8*D_MODEL*D_MODEL/1024, 256, 0, stream>>>(x, wq, wk, wv, wo, xb, wqkv, wob);

  dim3 gqkv(NQKV/128, NTOK/128);
  gemm8<bf16_t, true><<<gqkv, 256, 0, stream>>>(xb, wqkv, QK, Vtb, pos, NTOK, NQKV, D_MODEL);

  dim3 gattn(32, 144);
  attn14<<<gattn, 64, 0, stream>>>(QK, Vtb, pOA, pOB, pML);

  dim3 gcomb(64, 32);
  combine<<<gcomb, 128, 0, stream>>>(pOA, pOB, pML, Of);

  dim3 gout(D_MODEL/128, NTOK/128);
  gemm8<float, false><<<gout, 256, 0, stream>>>(Of, wob, out, nullptr, nullptr, NTOK, D_MODEL, D_MODEL);
}

// Round 15
// 125.030 us; speedup vs baseline: 1.0801x; 1.0801x over previous
//
#include <hip/hip_runtime.h>
#include <hip/hip_bf16.h>

typedef __bf16 bf16_t;
typedef __bf16 bf16x8 __attribute__((ext_vector_type(8)));
typedef __bf16 bf16x4 __attribute__((ext_vector_type(4)));
typedef float  f32x4  __attribute__((ext_vector_type(4)));
typedef float  f32x16 __attribute__((ext_vector_type(16)));
typedef unsigned int u32;
typedef unsigned int u32x2v __attribute__((ext_vector_type(2)));
typedef unsigned int u32x4v __attribute__((ext_vector_type(4)));

#define D_MODEL   1024
#define NQKV      3072
#define NUM_HEADS 16
#define HEAD_DIM  64
#define SEQ       2048
#define BATCH     2
#define NTOK      4096
// 0.125 * log2(e): folded into Q so softmax uses exp2 directly
#define SM_SCALE_LOG2E 0.18033688011112042f
#define LOG2_THETA 13.287712379549449f
#define NEG_BIG  (-3.0e38f)

// XOR slot swizzle for LDS tiles with 128-byte rows
__device__ __forceinline__ int swz128(int row, int bytecol) {
  return row*128 + ((((bytecol>>4) ^ (row&7))<<4) | (bytecol & 15));
}

__device__ __forceinline__ void gload16(const void* g, void* l) {
  __builtin_amdgcn_global_load_lds((const __attribute__((address_space(1))) u32*)g,
                                   (__attribute__((address_space(3))) u32*)l, 16, 0, 0);
}

__device__ __forceinline__ u32 cvtpk_bf16(float a, float b) {
  u32 r;
  asm("v_cvt_pk_bf16_f32 %0, %1, %2" : "=v"(r) : "v"(a), "v"(b));
  return r;
}

// permlane32_swap: res0 = [a.lo | b.lo], res1 = [a.hi | b.hi]
__device__ __forceinline__ void plswap(u32 &a, u32 &b) {
#if __has_builtin(__builtin_amdgcn_permlane32_swap)
  u32x2v r = __builtin_amdgcn_permlane32_swap(a, b, false, false);
  a = r[0]; b = r[1];
#else
  u32 xa = __shfl_xor((unsigned)a, 32, 64);
  u32 xb = __shfl_xor((unsigned)b, 32, 64);
  bool hi = (threadIdx.x & 32) != 0;
  a = hi ? xb : a;
  b = hi ? b : xa;
#endif
}

// 96 slots/bh: s<32 -> full q-wave s; s>=32 -> e=s-32, qw=32+(e>>1), half e&1.
__device__ const unsigned char slot_order96[96] = {
  30,31,88,90,92,93,94,95,
  28,29,80,82,84,85,86,87,89,91,
  26,27,72,74,76,77,78,79,81,83,
  24,25,64,66,68,69,70,71,73,75,
  22,23,56,58,60,61,62,63,65,67,
  20,21,48,50,52,53,54,55,57,59,
  18,19,40,42,44,45,46,47,49,51,
  16,17,32,34,36,37,38,39,41,43,
  14,15,33,35,
  12,13, 10,11, 8,9, 6,7, 4,5, 2,3, 0,1
};

// ---------------- fp32 -> bf16 conversion, single kernel ----------------
__global__ void cvt_all(const float* __restrict__ x,  const float* __restrict__ wq,
                        const float* __restrict__ wk, const float* __restrict__ wv,
                        const float* __restrict__ wo,
                        bf16_t* __restrict__ xb, bf16_t* __restrict__ wqkv,
                        bf16_t* __restrict__ wob) {
  const int NX = NTOK*D_MODEL;      // 4M
  const int NW = D_MODEL*D_MODEL;   // 1M
  int i = (blockIdx.x*256 + threadIdx.x)*4;
  float4 v; bf16_t* dst;
  if (i < NX) { v = *reinterpret_cast<const float4*>(x + i); dst = xb + i; }
  else {
    int k = i - NX;
    if      (k <   NW) { v = *reinterpret_cast<const float4*>(wq + k);        dst = wqkv + k; }
    else if (k < 2*NW) { v = *reinterpret_cast<const float4*>(wk + k -   NW); dst = wqkv + k; }
    else if (k < 3*NW) { v = *reinterpret_cast<const float4*>(wv + k - 2*NW); dst = wqkv + k; }
    else               { v = *reinterpret_cast<const float4*>(wo + k - 3*NW); dst = wob + k - 3*NW; }
  }
  bf16x4 o; o[0]=(bf16_t)v.x; o[1]=(bf16_t)v.y; o[2]=(bf16_t)v.z; o[3]=(bf16_t)v.w;
  *reinterpret_cast<bf16x4*>(dst) = o;
}

// ---------------- GEMM: C[M,N]=A[M,K]*B[N,K]^T — 4-slot counted-vmcnt -------
// If QKV: RoPE fused in the epilogue for Q,K columns; V third -> Vt transposed.
template<typename OutT, bool QKV>
__global__ __launch_bounds__(256, 1) void gemm8(const bf16_t* __restrict__ A,
                                                const bf16_t* __restrict__ B,
                                                OutT* __restrict__ C,
                                                bf16_t* __restrict__ Vt,
                                                const int* __restrict__ pos,
                                                int M, int N, int K) {
  __shared__ __align__(16) char lds[4][32768];   // per slot: [0,16K)=A, [16K,32K)=B
  int tid = threadIdx.x;
  int n0 = blockIdx.x*128, m0 = blockIdx.y*128;
  int wid = tid>>6, lane = tid&63;
  int wr = wid>>1, wc = wid&1;
  int lr = lane&15, lg = lane>>4;

  const int nT = K >> 6;

  int srow = tid >> 3;
  int sc8  = (tid & 7) ^ (srow & 7);
  const bf16_t* ga = A + (size_t)(m0 + srow)*K + sc8*8;
  const bf16_t* gb = B + (size_t)(n0 + srow)*K + sc8*8;

  f32x4 acc[4][4];
  #pragma unroll
  for (int a=0;a<4;a++)
    #pragma unroll
    for (int b=0;b<4;b++) acc[a][b] = (f32x4){0.f,0.f,0.f,0.f};

  auto stage = [&](int t) {
    char* s = lds[t&3];
    int k0 = t << 6;
    #pragma unroll
    for (int g=0; g<4; g++)
      gload16(ga + (size_t)(g*32)*K + k0, s + g*4096 + tid*16);
    #pragma unroll
    for (int g=0; g<4; g++)
      gload16(gb + (size_t)(g*32)*K + k0, s + 16384 + g*4096 + tid*16);
  };

  stage(0);
  if (nT > 1) stage(1);
  asm volatile("s_waitcnt vmcnt(8)" ::: "memory");
  __builtin_amdgcn_sched_barrier(0);
  __builtin_amdgcn_s_barrier();

  for (int t = 0; t < nT; ++t) {
    char* sA = lds[t&3];
    char* sB = sA + 16384;

    bf16x8 bq[4][2], aq[2][2];
    #pragma unroll
    for (int ni=0; ni<4; ni++)
      #pragma unroll
      for (int ks=0; ks<2; ks++)
        bq[ni][ks] = *reinterpret_cast<const bf16x8*>(sB + swz128(wc*64+ni*16+lr, ks*64+lg*16));
    #pragma unroll
    for (int mi=0; mi<2; mi++)
      #pragma unroll
      for (int ks=0; ks<2; ks++)
        aq[mi][ks] = *reinterpret_cast<const bf16x8*>(sA + swz128(wr*64+mi*16+lr, ks*64+lg*16));
    if (t + 2 < nT) stage(t + 2);
    asm volatile("s_waitcnt lgkmcnt(0)" ::: "memory");
    __builtin_amdgcn_sched_barrier(0);
    __builtin_amdgcn_s_setprio(1);
    #pragma unroll
    for (int mi=0; mi<2; mi++)
      #pragma unroll
      for (int ni=0; ni<4; ni++)
        #pragma unroll
        for (int ks=0; ks<2; ks++)
          acc[mi][ni] = __builtin_amdgcn_mfma_f32_16x16x32_bf16(aq[mi][ks], bq[ni][ks], acc[mi][ni], 0, 0, 0);
    __builtin_amdgcn_s_setprio(0);
    __builtin_amdgcn_s_barrier();

    bf16x8 aq2[2][2];
    #pragma unroll
    for (int mi=0; mi<2; mi++)
      #pragma unroll
      for (int ks=0; ks<2; ks++)
        aq2[mi][ks] = *reinterpret_cast<const bf16x8*>(sA + swz128(wr*64+(mi+2)*16+lr, ks*64+lg*16));
    asm volatile("s_waitcnt lgkmcnt(0)" ::: "memory");
    __builtin_amdgcn_sched_barrier(0);
    __builtin_amdgcn_s_setprio(1);
    #pragma unroll
    for (int mi=0; mi<2; mi++)
      #pragma unroll
      for (int ni=0; ni<4; ni++)
        #pragma unroll
        for (int ks=0; ks<2; ks++)
          acc[mi+2][ni] = __builtin_amdgcn_mfma_f32_16x16x32_bf16(aq2[mi][ks], bq[ni][ks], acc[mi+2][ni], 0, 0, 0);
    __builtin_amdgcn_s_setprio(0);
    if (t + 2 < nT)      { asm volatile("s_waitcnt vmcnt(8)" ::: "memory"); }
    else if (t + 1 < nT) { asm volatile("s_waitcnt vmcnt(0)" ::: "memory"); }
    __builtin_amdgcn_sched_barrier(0);
    __builtin_amdgcn_s_barrier();
  }

  if (QKV && n0 < 2*D_MODEL) {
    // RoPE fused epilogue for Q,K projections.
    bool isQ = (n0 < D_MODEL);
    float fr[4];
    #pragma unroll
    for (int ni=0; ni<4; ni++) {
      int j = ((wc*64 + ni*16 + lr) & 63) >> 1;
      fr[ni] = exp2f(-(float)j * (LOG2_THETA/32.0f));
    }
    #pragma unroll
    for (int mi=0; mi<4; mi++)
      #pragma unroll
      for (int r=0; r<4; r++) {
        int m = m0 + wr*64 + mi*16 + lg*4 + r;
        float pt = (float)pos[m & (SEQ-1)];
        #pragma unroll
        for (int ni=0; ni<4; ni++) {
          int n = n0 + wc*64 + ni*16 + lr;
          float v = acc[mi][ni][r];
          float p = __shfl_xor(v, 1, 64);
          float sv, cv;
          __sincosf(pt * fr[ni], &sv, &cv);
          float o = (n & 1) ? (p*sv + v*cv) : (v*cv - p*sv);
          if (isQ) o *= SM_SCALE_LOG2E;
          C[(size_t)m*N + n] = (OutT)o;
        }
      }
  } else if (!QKV) {
    #pragma unroll
    for (int mi=0;mi<4;mi++)
      #pragma unroll
      for (int ni=0;ni<4;ni++)
        #pragma unroll
        for (int r=0;r<4;r++) {
          int m = m0 + wr*64 + mi*16 + lg*4 + r;
          int n = n0 + wc*64 + ni*16 + lr;
          C[(size_t)m*N + n] = (OutT)acc[mi][ni][r];
        }
  } else {
    #pragma unroll
    for (int mi=0;mi<4;mi++)
      #pragma unroll
      for (int ni=0;ni<4;ni++)
        #pragma unroll
        for (int r=0;r<4;r++) {
          int m = m0 + wr*64 + mi*16 + lg*4 + r;
          int nl = n0 + wc*64 + ni*16 + lr - 2*D_MODEL;
          int h = nl >> 6, d = nl & 63;
          int bb = m >> 11, s = m & (SEQ-1);
          Vt[(((size_t)(bb*16 + h)*64 + d) << 11) + s] = (bf16_t)acc[mi][ni][r];
        }
  }
}

// ---------------- Flash causal attention: 1-wave, single-buffered K+V -------
// (attn9 + T13 defer-max) grid (32 bh, 96 slots), block = ONE wave, no
// barriers. LDS 16 KB. Per iter: ds_read ALL K,V frags to regs, lgkm(0),
// re-stage K(t+1),V(t+1) into same buffers (prefetch window = full iteration).
__global__ __launch_bounds__(64, 2) void attn9(const bf16_t* __restrict__ QKV,
                                               const bf16_t* __restrict__ Vt,
                                               bf16_t* __restrict__ pO,
                                               float2* __restrict__ pML) {
  __shared__ __align__(16) char sK[64*128];
  __shared__ __align__(16) char sV[64*128];

  int bh = blockIdx.x;
  int b = bh >> 4, h = bh & 15;
  int lane = threadIdx.x & 63;
  int q32 = lane & 31, hi = lane >> 5;
  int rsub = lane >> 3, sg = (lane & 7) ^ rsub;

  int s = slot_order96[blockIdx.y];
  int qw, t0, t1;
  if (s < 32) { qw = s; t0 = 0; t1 = (s >> 1) + 1; }
  else {
    int e = s - 32;
    qw = 32 + (e >> 1);
    int nt = (qw >> 1) + 1, h0 = (nt + 1) >> 1;
    t0 = (e & 1) ? h0 : 0;
    t1 = (e & 1) ? nt : h0;
  }
  int qt   = qw >> 1;
  int slot = bh*96 + s;
  int qg   = qw*32 + q32;

  bf16x8 qf[4];
  const bf16_t* qrow = QKV + (size_t)(b*SEQ + qw*32 + q32)*NQKV + h*64 + hi*8;
  #pragma unroll
  for (int d=0; d<4; d++) qf[d] = *reinterpret_cast<const bf16x8*>(qrow + d*16);

  const bf16_t* kgb = QKV + D_MODEL + ((size_t)(b*SEQ) + rsub)*NQKV + h*64 + sg*8;
  const bf16_t* vgb = Vt + (size_t)bh*64*SEQ + (size_t)rsub*SEQ + sg*8;

  auto stageK = [&](int t) {
    const bf16_t* src = kgb + (size_t)t*64*NQKV;
    #pragma unroll
    for (int c=0;c<8;c++)
      gload16(src + (size_t)(8*c)*NQKV, sK + c*1024 + lane*16);
  };
  auto stageV = [&](int t) {
    const bf16_t* src = vgb + t*64;
    #pragma unroll
    for (int c=0;c<8;c++)
      gload16(src + (size_t)(8*c)*SEQ, sV + c*1024 + lane*16);
  };

  f32x16 O0 = (f32x16)0.0f, O1 = (f32x16)0.0f;
  float mrun = NEG_BIG, lrun = 0.f;

  stageK(t0); stageV(t0);
  asm volatile("s_waitcnt vmcnt(0)" ::: "memory");
  __builtin_amdgcn_sched_barrier(0);

  for (int ti = t0; ti < t1; ++ti) {
    bf16x8 k0f[4], k1f[4], v0f[4], v1f[4];
    #pragma unroll
    for (int ds=0; ds<4; ds++) {
      k0f[ds] = *reinterpret_cast<const bf16x8*>(sK + swz128(q32,    ds*32 + hi*16));
      k1f[ds] = *reinterpret_cast<const bf16x8*>(sK + swz128(32+q32, ds*32 + hi*16));
      v0f[ds] = *reinterpret_cast<const bf16x8*>(sV + swz128(q32,    ds*32 + hi*16));
      v1f[ds] = *reinterpret_cast<const bf16x8*>(sV + swz128(32+q32, ds*32 + hi*16));
    }
    asm volatile("s_waitcnt lgkmcnt(0)" ::: "memory");
    __builtin_amdgcn_sched_barrier(0);
    if (ti + 1 < t1) { stageK(ti + 1); stageV(ti + 1); }

    f32x16 p0 = (f32x16)0.0f, p1 = (f32x16)0.0f;
    __builtin_amdgcn_s_setprio(1);
    #pragma unroll
    for (int ds=0; ds<4; ds++) {
      p0 = __builtin_amdgcn_mfma_f32_32x32x16_bf16(k0f[ds], qf[ds], p0, 0, 0, 0);
      p1 = __builtin_amdgcn_mfma_f32_32x32x16_bf16(k1f[ds], qf[ds], p1, 0, 0, 0);
    }
    __builtin_amdgcn_s_setprio(0);

    if (ti == qt) {
      #pragma unroll
      for (int r=0; r<16; r++) {
        int kg = ti*64 + (r&3) + 8*(r>>2) + 4*hi;
        if (kg      > qg) p0[r] = NEG_BIG;
        if (kg + 32 > qg) p1[r] = NEG_BIG;
      }
    }

    float mx[8];
    #pragma unroll
    for (int r=0;r<8;r++) mx[r] = fmaxf(fmaxf(p0[r],p0[r+8]), fmaxf(p1[r],p1[r+8]));
    #pragma unroll
    for (int st=4; st>0; st>>=1)
      #pragma unroll
      for (int r=0;r<st;r++) mx[r] = fmaxf(mx[r], mx[r+st]);
    float mt = fmaxf(mx[0], __shfl_xor(mx[0], 32, 64));

    // T13 defer-max: rescale only when the running max grew by > 8
    if (!__all(mt <= mrun + 8.0f)) {
      float mnew  = fmaxf(mrun, mt);
      float alpha = exp2f(mrun - mnew);
      lrun *= alpha;
      O0 *= alpha; O1 *= alpha;
      mrun = mnew;
    }
    #pragma unroll
    for (int r=0; r<16; r++) {
      p0[r] = exp2f(p0[r] - mrun);
      p1[r] = exp2f(p1[r] - mrun);
    }
    float sx[8];
    #pragma unroll
    for (int r=0;r<8;r++) sx[r] = (p0[r]+p0[r+8]) + (p1[r]+p1[r+8]);
    #pragma unroll
    for (int st=4; st>0; st>>=1)
      #pragma unroll
      for (int r=0;r<st;r++) sx[r] += sx[r+st];
    lrun += sx[0] + __shfl_xor(sx[0], 32, 64);

    u32 pk0[8], pk1[8];
    #pragma unroll
    for (int i2=0; i2<8; i2++) {
      pk0[i2] = cvtpk_bf16(p0[2*i2], p0[2*i2+1]);
      pk1[i2] = cvtpk_bf16(p1[2*i2], p1[2*i2+1]);
    }
    plswap(pk0[0], pk0[2]); plswap(pk0[1], pk0[3]);
    plswap(pk0[4], pk0[6]); plswap(pk0[5], pk0[7]);
    plswap(pk1[0], pk1[2]); plswap(pk1[1], pk1[3]);
    plswap(pk1[4], pk1[6]); plswap(pk1[5], pk1[7]);

    bf16x8 pa[4];
    pa[0] = __builtin_bit_cast(bf16x8, (u32x4v){pk0[0],pk0[1],pk0[2],pk0[3]});
    pa[1] = __builtin_bit_cast(bf16x8, (u32x4v){pk0[4],pk0[5],pk0[6],pk0[7]});
    pa[2] = __builtin_bit_cast(bf16x8, (u32x4v){pk1[0],pk1[1],pk1[2],pk1[3]});
    pa[3] = __builtin_bit_cast(bf16x8, (u32x4v){pk1[4],pk1[5],pk1[6],pk1[7]});

    __builtin_amdgcn_s_setprio(1);
    #pragma unroll
    for (int ks=0; ks<4; ks++) {
      O0 = __builtin_amdgcn_mfma_f32_32x32x16_bf16(v0f[ks], pa[ks], O0, 0, 0, 0);
      O1 = __builtin_amdgcn_mfma_f32_32x32x16_bf16(v1f[ks], pa[ks], O1, 0, 0, 0);
    }
    __builtin_amdgcn_s_setprio(0);

    if (ti + 1 < t1) {
      asm volatile("s_waitcnt vmcnt(0)" ::: "memory");
      __builtin_amdgcn_sched_barrier(0);
    }
  }

  bf16_t* prow = pO + ((size_t)slot*2048 + q32*64);
  #pragma unroll
  for (int rg=0; rg<4; rg++) {
    int d0 = 8*rg + 4*hi;
    u32 a0 = cvtpk_bf16(O0[4*rg],   O0[4*rg+1]);
    u32 a1 = cvtpk_bf16(O0[4*rg+2], O0[4*rg+3]);
    *reinterpret_cast<u32x2v*>(prow + d0) = (u32x2v){a0, a1};
    u32 b0 = cvtpk_bf16(O1[4*rg],   O1[4*rg+1]);
    u32 b1 = cvtpk_bf16(O1[4*rg+2], O1[4*rg+3]);
    *reinterpret_cast<u32x2v*>(prow + 32 + d0) = (u32x2v){b0, b1};
  }
  if (hi == 0)
    pML[slot*32 + q32] = make_float2(mrun, lrun);
}

// ---------------- combine partials -> Of ----------------
__global__ __launch_bounds__(128) void combine(const bf16_t* __restrict__ pO,
                                               const float2* __restrict__ pML,
                                               bf16_t* __restrict__ Of) {
  int qw = blockIdx.x, bh = blockIdx.y;
  int b = bh >> 4, h = bh & 15;
  int t = threadIdx.x;
  int q = t >> 2, d0 = (t & 3) * 16;
  bf16x8 r0, r1;
  if (qw < 32) {
    int slot = bh*96 + qw;
    float2 ml = pML[slot*32 + q];
    float inv = 1.0f / ml.y;
    const bf16x8* src = reinterpret_cast<const bf16x8*>(pO + (size_t)slot*2048 + q*64 + d0);
    bf16x8 o0 = src[0], o1 = src[1];
    #pragma unroll
    for (int i=0;i<8;i++) {
      r0[i] = (bf16_t)((float)o0[i]*inv);
      r1[i] = (bf16_t)((float)o1[i]*inv);
    }
  } else {
    int s0 = bh*96 + 32 + (qw-32)*2;
    float2 mlA = pML[s0*32 + q];
    float2 mlB = pML[(s0+1)*32 + q];
    float m  = fmaxf(mlA.x, mlB.x);
    float a0 = exp2f(mlA.x - m), a1 = exp2f(mlB.x - m);
    float inv = 1.0f / (a0*mlA.y + a1*mlB.y);
    a0 *= inv; a1 *= inv;
    const bf16x8* sA = reinterpret_cast<const bf16x8*>(pO + (size_t)s0*2048 + q*64 + d0);
    const bf16x8* sB = reinterpret_cast<const bf16x8*>(pO + (size_t)(s0+1)*2048 + q*64 + d0);
    bf16x8 oa0 = sA[0], oa1 = sA[1], ob0 = sB[0], ob1 = sB[1];
    #pragma unroll
    for (int i=0;i<8;i++) {
      r0[i] = (bf16_t)(a0*(float)oa0[i] + a1*(float)ob0[i]);
      r1[i] = (bf16_t)(a0*(float)oa1[i] + a1*(float)ob1[i]);
    }
  }
  bf16x8* dst = reinterpret_cast<bf16x8*>(Of + ((size_t)(b*SEQ) + qw*32 + q)*D_MODEL + h*64 + d0);
  dst[0] = r0; dst[1] = r1;
}

// ---------------- launch ----------------
// Workspace lifetimes:
//   [ 0,  8) MB xb   (phases 1-2)  -> pO head  (attn/combine)
//   [ 8, 14) MB wqkv (phases 1-2)  -> pO tail (to 12.6MB) + pML (at 13MB)
//   [14, 16) MB wob  (all phases)
//   [16, 40) MB QKV  (gemm->attn)
//   [40, 48) MB Vtb  (gemm->attn)  -> Of (combine->out-gemm)
extern "C" void kernel_launch(void* const* d_in, const int* in_sizes, int n_in,
                              void* d_out, int out_size, void* d_ws, size_t ws_size,
                              hipStream_t stream) {
  const float* x   = (const float*)d_in[0];
  const int*   pos = (const int*)  d_in[1];
  const float* wq  = (const float*)d_in[2];
  const float* wk  = (const float*)d_in[3];
  const float* wv  = (const float*)d_in[4];
  const float* wo  = (const float*)d_in[5];
  float* out = (float*)d_out;

  char* ws = (char*)d_ws;
  bf16_t* xb   = (bf16_t*)(ws);
  bf16_t* wqkv = (bf16_t*)(ws + ( 8u<<20));
  bf16_t* wob  = (bf16_t*)(ws + (14u<<20));
  bf16_t* QKV  = (bf16_t*)(ws + (16u<<20));
  bf16_t* Vtb  = (bf16_t*)(ws + (40u<<20));
  bf16_t* pO   = (bf16_t*)(ws);                 // 32*96*2048*2B = 12.6 MB
  float2* pML  = (float2*)(ws + (13u<<20));     // 32*96*32*8B = 768 KB
  bf16_t* Of   = (bf16_t*)(ws + (40u<<20));     // overlays dead Vtb

  cvt_all<<<8*D_MODEL*D_MODEL/1024, 256, 0, stream>>>(x, wq, wk, wv, wo, xb, wqkv, wob);

  dim3 gqkv(NQKV/128, NTOK/128);
  gemm8<bf16_t, true><<<gqkv, 256, 0, stream>>>(xb, wqkv, QKV, Vtb, pos, NTOK, NQKV, D_MODEL);

  dim3 gattn(32, 96);
  attn9<<<gattn, 64, 0, stream>>>(QKV, Vtb, pO, pML);

  dim3 gcomb(64, 32);
  combine<<<gcomb, 128, 0, stream>>>(pO, pML, Of);

  dim3 gout(D_MODEL/128, NTOK/128);
  gemm8<float, false><<<gout, 256, 0, stream>>>(Of, wob, out, nullptr, nullptr, NTOK, D_MODEL, D_MODEL);
}

// Round 16
// 120.674 us; speedup vs baseline: 1.1191x; 1.0361x over previous
//
#include <hip/hip_runtime.h>
#include <hip/hip_bf16.h>

typedef __bf16 bf16_t;
typedef __bf16 bf16x8 __attribute__((ext_vector_type(8)));
typedef __bf16 bf16x4 __attribute__((ext_vector_type(4)));
typedef float  f32x4  __attribute__((ext_vector_type(4)));
typedef float  f32x16 __attribute__((ext_vector_type(16)));
typedef unsigned int u32;
typedef unsigned int u32x2v __attribute__((ext_vector_type(2)));
typedef unsigned int u32x4v __attribute__((ext_vector_type(4)));

#define D_MODEL   1024
#define NQKV      3072
#define NUM_HEADS 16
#define HEAD_DIM  64
#define SEQ       2048
#define BATCH     2
#define NTOK      4096
// 0.125 * log2(e): folded into Q so softmax uses exp2 directly
#define SM_SCALE_LOG2E 0.18033688011112042f
#define LOG2_THETA 13.287712379549449f
#define NEG_BIG  (-3.0e38f)

// XOR slot swizzle for LDS tiles with 128-byte rows
__device__ __forceinline__ int swz128(int row, int bytecol) {
  return row*128 + ((((bytecol>>4) ^ (row&7))<<4) | (bytecol & 15));
}

__device__ __forceinline__ void gload16(const void* g, void* l) {
  __builtin_amdgcn_global_load_lds((const __attribute__((address_space(1))) u32*)g,
                                   (__attribute__((address_space(3))) u32*)l, 16, 0, 0);
}

__device__ __forceinline__ u32 cvtpk_bf16(float a, float b) {
  u32 r;
  asm("v_cvt_pk_bf16_f32 %0, %1, %2" : "=v"(r) : "v"(a), "v"(b));
  return r;
}

// permlane32_swap: res0 = [a.lo | b.lo], res1 = [a.hi | b.hi]
__device__ __forceinline__ void plswap(u32 &a, u32 &b) {
#if __has_builtin(__builtin_amdgcn_permlane32_swap)
  u32x2v r = __builtin_amdgcn_permlane32_swap(a, b, false, false);
  a = r[0]; b = r[1];
#else
  u32 xa = __shfl_xor((unsigned)a, 32, 64);
  u32 xb = __shfl_xor((unsigned)b, 32, 64);
  bool hi = (threadIdx.x & 32) != 0;
  a = hi ? xb : a;
  b = hi ? b : xa;
#endif
}

// 96 slots/bh: s<32 -> full q-wave s; s>=32 -> e=s-32, qw=32+(e>>1), half e&1.
__device__ const unsigned char slot_order96[96] = {
  30,31,88,90,92,93,94,95,
  28,29,80,82,84,85,86,87,89,91,
  26,27,72,74,76,77,78,79,81,83,
  24,25,64,66,68,69,70,71,73,75,
  22,23,56,58,60,61,62,63,65,67,
  20,21,48,50,52,53,54,55,57,59,
  18,19,40,42,44,45,46,47,49,51,
  16,17,32,34,36,37,38,39,41,43,
  14,15,33,35,
  12,13, 10,11, 8,9, 6,7, 4,5, 2,3, 0,1
};

// ---------------- fp32 -> bf16 conversion, single kernel ----------------
__global__ void cvt_all(const float* __restrict__ x,  const float* __restrict__ wq,
                        const float* __restrict__ wk, const float* __restrict__ wv,
                        const float* __restrict__ wo,
                        bf16_t* __restrict__ xb, bf16_t* __restrict__ wqkv,
                        bf16_t* __restrict__ wob) {
  const int NX = NTOK*D_MODEL;      // 4M
  const int NW = D_MODEL*D_MODEL;   // 1M
  int i = (blockIdx.x*256 + threadIdx.x)*4;
  float4 v; bf16_t* dst;
  if (i < NX) { v = *reinterpret_cast<const float4*>(x + i); dst = xb + i; }
  else {
    int k = i - NX;
    if      (k <   NW) { v = *reinterpret_cast<const float4*>(wq + k);        dst = wqkv + k; }
    else if (k < 2*NW) { v = *reinterpret_cast<const float4*>(wk + k -   NW); dst = wqkv + k; }
    else if (k < 3*NW) { v = *reinterpret_cast<const float4*>(wv + k - 2*NW); dst = wqkv + k; }
    else               { v = *reinterpret_cast<const float4*>(wo + k - 3*NW); dst = wob + k - 3*NW; }
  }
  bf16x4 o; o[0]=(bf16_t)v.x; o[1]=(bf16_t)v.y; o[2]=(bf16_t)v.z; o[3]=(bf16_t)v.w;
  *reinterpret_cast<bf16x4*>(dst) = o;
}

// ---------------- QKV GEMM: 256x128 tile, 8 waves, 3-slot counted-vmcnt -----
// C = A[M,K]*B[N,K]^T with fused RoPE on Q,K columns; V third -> Vt transposed.
// LDS 3 slots x (A 32KB + B 16KB) = 144KB -> 1 block/CU, 8 waves = 2/SIMD.
// Stage t+2 into slot (t+2)%3 (last read iter t-1, freed at its end barrier);
// end-of-iter vmcnt(6) waits tile t+1, leaves t+2's 6 loads in flight.
__global__ __launch_bounds__(512, 1) void gemm_qkv(const bf16_t* __restrict__ A,
                                                   const bf16_t* __restrict__ B,
                                                   bf16_t* __restrict__ C,
                                                   bf16_t* __restrict__ Vt,
                                                   const int* __restrict__ pos) {
  const int K = D_MODEL, N = NQKV;
  __shared__ __align__(16) char lds[3][49152];   // per slot: [0,32K)=A, [32K,48K)=B
  int tid = threadIdx.x;
  int n0 = blockIdx.x*128, m0 = blockIdx.y*256;
  int wid = tid>>6, lane = tid&63;
  int wr = wid>>1, wc = wid&1;          // wave tile: rows wr*64, cols wc*64
  int lr = lane&15, lg = lane>>4;

  const int nT = K >> 6;                // 16

  int srow = tid >> 3;                  // 0..63
  int sc8  = (tid & 7) ^ (srow & 7);
  const bf16_t* ga = A + (size_t)(m0 + srow)*K + sc8*8;
  const bf16_t* gb = B + (size_t)(n0 + srow)*K + sc8*8;

  f32x4 acc[4][4];
  #pragma unroll
  for (int a=0;a<4;a++)
    #pragma unroll
    for (int b=0;b<4;b++) acc[a][b] = (f32x4){0.f,0.f,0.f,0.f};

  auto stage = [&](int t) {   // 6 gloads: A 4x64rows + B 2x64rows
    char* s = lds[t % 3];
    int k0 = t << 6;
    #pragma unroll
    for (int g=0; g<4; g++)
      gload16(ga + (size_t)(g*64)*K + k0, s + g*8192 + tid*16);
    #pragma unroll
    for (int g=0; g<2; g++)
      gload16(gb + (size_t)(g*64)*K + k0, s + 32768 + g*8192 + tid*16);
  };

  stage(0);
  stage(1);
  asm volatile("s_waitcnt vmcnt(6)" ::: "memory");
  __builtin_amdgcn_sched_barrier(0);
  __builtin_amdgcn_s_barrier();

  for (int t = 0; t < nT; ++t) {
    char* sA = lds[t % 3];
    char* sB = sA + 32768;

    // ---- phase 0: B all + A mi0-1; stage t+2; MFMA {mi0,mi1} ----
    bf16x8 bq[4][2], aq[2][2];
    #pragma unroll
    for (int ni=0; ni<4; ni++)
      #pragma unroll
      for (int ks=0; ks<2; ks++)
        bq[ni][ks] = *reinterpret_cast<const bf16x8*>(sB + swz128(wc*64+ni*16+lr, ks*64+lg*16));
    #pragma unroll
    for (int mi=0; mi<2; mi++)
      #pragma unroll
      for (int ks=0; ks<2; ks++)
        aq[mi][ks] = *reinterpret_cast<const bf16x8*>(sA + swz128(wr*64+mi*16+lr, ks*64+lg*16));
    if (t + 2 < nT) stage(t + 2);
    asm volatile("s_waitcnt lgkmcnt(0)" ::: "memory");
    __builtin_amdgcn_sched_barrier(0);
    __builtin_amdgcn_s_setprio(1);
    #pragma unroll
    for (int mi=0; mi<2; mi++)
      #pragma unroll
      for (int ni=0; ni<4; ni++)
        #pragma unroll
        for (int ks=0; ks<2; ks++)
          acc[mi][ni] = __builtin_amdgcn_mfma_f32_16x16x32_bf16(aq[mi][ks], bq[ni][ks], acc[mi][ni], 0, 0, 0);
    __builtin_amdgcn_s_setprio(0);
    __builtin_amdgcn_s_barrier();

    // ---- phase 1: A mi2-3; MFMA {mi2,mi3}; counted end-wait ----
    bf16x8 aq2[2][2];
    #pragma unroll
    for (int mi=0; mi<2; mi++)
      #pragma unroll
      for (int ks=0; ks<2; ks++)
        aq2[mi][ks] = *reinterpret_cast<const bf16x8*>(sA + swz128(wr*64+(mi+2)*16+lr, ks*64+lg*16));
    asm volatile("s_waitcnt lgkmcnt(0)" ::: "memory");
    __builtin_amdgcn_sched_barrier(0);
    __builtin_amdgcn_s_setprio(1);
    #pragma unroll
    for (int mi=0; mi<2; mi++)
      #pragma unroll
      for (int ni=0; ni<4; ni++)
        #pragma unroll
        for (int ks=0; ks<2; ks++)
          acc[mi+2][ni] = __builtin_amdgcn_mfma_f32_16x16x32_bf16(aq2[mi][ks], bq[ni][ks], acc[mi+2][ni], 0, 0, 0);
    __builtin_amdgcn_s_setprio(0);
    if (t + 2 < nT)      { asm volatile("s_waitcnt vmcnt(6)" ::: "memory"); }
    else if (t + 1 < nT) { asm volatile("s_waitcnt vmcnt(0)" ::: "memory"); }
    __builtin_amdgcn_sched_barrier(0);
    __builtin_amdgcn_s_barrier();
  }

  if (n0 < 2*D_MODEL) {
    // RoPE fused epilogue for Q,K projections.
    bool isQ = (n0 < D_MODEL);
    float fr[4];
    #pragma unroll
    for (int ni=0; ni<4; ni++) {
      int j = ((wc*64 + ni*16 + lr) & 63) >> 1;
      fr[ni] = exp2f(-(float)j * (LOG2_THETA/32.0f));
    }
    #pragma unroll
    for (int mi=0; mi<4; mi++)
      #pragma unroll
      for (int r=0; r<4; r++) {
        int m = m0 + wr*64 + mi*16 + lg*4 + r;
        float pt = (float)pos[m & (SEQ-1)];
        #pragma unroll
        for (int ni=0; ni<4; ni++) {
          int n = n0 + wc*64 + ni*16 + lr;
          float v = acc[mi][ni][r];
          float p = __shfl_xor(v, 1, 64);
          float sv, cv;
          __sincosf(pt * fr[ni], &sv, &cv);
          float o = (n & 1) ? (p*sv + v*cv) : (v*cv - p*sv);
          if (isQ) o *= SM_SCALE_LOG2E;
          C[(size_t)m*N + n] = (bf16_t)o;
        }
      }
  } else {
    #pragma unroll
    for (int mi=0;mi<4;mi++)
      #pragma unroll
      for (int ni=0;ni<4;ni++)
        #pragma unroll
        for (int r=0;r<4;r++) {
          int m = m0 + wr*64 + mi*16 + lg*4 + r;
          int nl = n0 + wc*64 + ni*16 + lr - 2*D_MODEL;
          int h = nl >> 6, d = nl & 63;
          int bb = m >> 11, s = m & (SEQ-1);
          Vt[(((size_t)(bb*16 + h)*64 + d) << 11) + s] = (bf16_t)acc[mi][ni][r];
        }
  }
}

// ---------------- out GEMM: 128x128, 4-slot counted-vmcnt (gemm8) ----------
__global__ __launch_bounds__(256, 1) void gemm_out(const bf16_t* __restrict__ A,
                                                   const bf16_t* __restrict__ B,
                                                   float* __restrict__ C,
                                                   int M, int N, int K) {
  __shared__ __align__(16) char lds[4][32768];
  int tid = threadIdx.x;
  int n0 = blockIdx.x*128, m0 = blockIdx.y*128;
  int wid = tid>>6, lane = tid&63;
  int wr = wid>>1, wc = wid&1;
  int lr = lane&15, lg = lane>>4;

  const int nT = K >> 6;

  int srow = tid >> 3;
  int sc8  = (tid & 7) ^ (srow & 7);
  const bf16_t* ga = A + (size_t)(m0 + srow)*K + sc8*8;
  const bf16_t* gb = B + (size_t)(n0 + srow)*K + sc8*8;

  f32x4 acc[4][4];
  #pragma unroll
  for (int a=0;a<4;a++)
    #pragma unroll
    for (int b=0;b<4;b++) acc[a][b] = (f32x4){0.f,0.f,0.f,0.f};

  auto stage = [&](int t) {
    char* s = lds[t&3];
    int k0 = t << 6;
    #pragma unroll
    for (int g=0; g<4; g++)
      gload16(ga + (size_t)(g*32)*K + k0, s + g*4096 + tid*16);
    #pragma unroll
    for (int g=0; g<4; g++)
      gload16(gb + (size_t)(g*32)*K + k0, s + 16384 + g*4096 + tid*16);
  };

  stage(0);
  if (nT > 1) stage(1);
  asm volatile("s_waitcnt vmcnt(8)" ::: "memory");
  __builtin_amdgcn_sched_barrier(0);
  __builtin_amdgcn_s_barrier();

  for (int t = 0; t < nT; ++t) {
    char* sA = lds[t&3];
    char* sB = sA + 16384;

    bf16x8 bq[4][2], aq[2][2];
    #pragma unroll
    for (int ni=0; ni<4; ni++)
      #pragma unroll
      for (int ks=0; ks<2; ks++)
        bq[ni][ks] = *reinterpret_cast<const bf16x8*>(sB + swz128(wc*64+ni*16+lr, ks*64+lg*16));
    #pragma unroll
    for (int mi=0; mi<2; mi++)
      #pragma unroll
      for (int ks=0; ks<2; ks++)
        aq[mi][ks] = *reinterpret_cast<const bf16x8*>(sA + swz128(wr*64+mi*16+lr, ks*64+lg*16));
    if (t + 2 < nT) stage(t + 2);
    asm volatile("s_waitcnt lgkmcnt(0)" ::: "memory");
    __builtin_amdgcn_sched_barrier(0);
    __builtin_amdgcn_s_setprio(1);
    #pragma unroll
    for (int mi=0; mi<2; mi++)
      #pragma unroll
      for (int ni=0; ni<4; ni++)
        #pragma unroll
        for (int ks=0; ks<2; ks++)
          acc[mi][ni] = __builtin_amdgcn_mfma_f32_16x16x32_bf16(aq[mi][ks], bq[ni][ks], acc[mi][ni], 0, 0, 0);
    __builtin_amdgcn_s_setprio(0);
    __builtin_amdgcn_s_barrier();

    bf16x8 aq2[2][2];
    #pragma unroll
    for (int mi=0; mi<2; mi++)
      #pragma unroll
      for (int ks=0; ks<2; ks++)
        aq2[mi][ks] = *reinterpret_cast<const bf16x8*>(sA + swz128(wr*64+(mi+2)*16+lr, ks*64+lg*16));
    asm volatile("s_waitcnt lgkmcnt(0)" ::: "memory");
    __builtin_amdgcn_sched_barrier(0);
    __builtin_amdgcn_s_setprio(1);
    #pragma unroll
    for (int mi=0; mi<2; mi++)
      #pragma unroll
      for (int ni=0; ni<4; ni++)
        #pragma unroll
        for (int ks=0; ks<2; ks++)
          acc[mi+2][ni] = __builtin_amdgcn_mfma_f32_16x16x32_bf16(aq2[mi][ks], bq[ni][ks], acc[mi+2][ni], 0, 0, 0);
    __builtin_amdgcn_s_setprio(0);
    if (t + 2 < nT)      { asm volatile("s_waitcnt vmcnt(8)" ::: "memory"); }
    else if (t + 1 < nT) { asm volatile("s_waitcnt vmcnt(0)" ::: "memory"); }
    __builtin_amdgcn_sched_barrier(0);
    __builtin_amdgcn_s_barrier();
  }

  #pragma unroll
  for (int mi=0;mi<4;mi++)
    #pragma unroll
    for (int ni=0;ni<4;ni++)
      #pragma unroll
      for (int r=0;r<4;r++) {
        int m = m0 + wr*64 + mi*16 + lg*4 + r;
        int n = n0 + wc*64 + ni*16 + lr;
        C[(size_t)m*N + n] = acc[mi][ni][r];
      }
}

// ---------------- Flash causal attention: 1-wave, single-buffered K+V -------
// (attn9 + T13) grid (32 bh, 96 slots), block = ONE wave, no barriers.
__global__ __launch_bounds__(64, 2) void attn9(const bf16_t* __restrict__ QKV,
                                               const bf16_t* __restrict__ Vt,
                                               bf16_t* __restrict__ pO,
                                               float2* __restrict__ pML) {
  __shared__ __align__(16) char sK[64*128];
  __shared__ __align__(16) char sV[64*128];

  int bh = blockIdx.x;
  int b = bh >> 4, h = bh & 15;
  int lane = threadIdx.x & 63;
  int q32 = lane & 31, hi = lane >> 5;
  int rsub = lane >> 3, sg = (lane & 7) ^ rsub;

  int s = slot_order96[blockIdx.y];
  int qw, t0, t1;
  if (s < 32) { qw = s; t0 = 0; t1 = (s >> 1) + 1; }
  else {
    int e = s - 32;
    qw = 32 + (e >> 1);
    int nt = (qw >> 1) + 1, h0 = (nt + 1) >> 1;
    t0 = (e & 1) ? h0 : 0;
    t1 = (e & 1) ? nt : h0;
  }
  int qt   = qw >> 1;
  int slot = bh*96 + s;
  int qg   = qw*32 + q32;

  bf16x8 qf[4];
  const bf16_t* qrow = QKV + (size_t)(b*SEQ + qw*32 + q32)*NQKV + h*64 + hi*8;
  #pragma unroll
  for (int d=0; d<4; d++) qf[d] = *reinterpret_cast<const bf16x8*>(qrow + d*16);

  const bf16_t* kgb = QKV + D_MODEL + ((size_t)(b*SEQ) + rsub)*NQKV + h*64 + sg*8;
  const bf16_t* vgb = Vt + (size_t)bh*64*SEQ + (size_t)rsub*SEQ + sg*8;

  auto stageK = [&](int t) {
    const bf16_t* src = kgb + (size_t)t*64*NQKV;
    #pragma unroll
    for (int c=0;c<8;c++)
      gload16(src + (size_t)(8*c)*NQKV, sK + c*1024 + lane*16);
  };
  auto stageV = [&](int t) {
    const bf16_t* src = vgb + t*64;
    #pragma unroll
    for (int c=0;c<8;c++)
      gload16(src + (size_t)(8*c)*SEQ, sV + c*1024 + lane*16);
  };

  f32x16 O0 = (f32x16)0.0f, O1 = (f32x16)0.0f;
  float mrun = NEG_BIG, lrun = 0.f;

  stageK(t0); stageV(t0);
  asm volatile("s_waitcnt vmcnt(0)" ::: "memory");
  __builtin_amdgcn_sched_barrier(0);

  for (int ti = t0; ti < t1; ++ti) {
    bf16x8 k0f[4], k1f[4], v0f[4], v1f[4];
    #pragma unroll
    for (int ds=0; ds<4; ds++) {
      k0f[ds] = *reinterpret_cast<const bf16x8*>(sK + swz128(q32,    ds*32 + hi*16));
      k1f[ds] = *reinterpret_cast<const bf16x8*>(sK + swz128(32+q32, ds*32 + hi*16));
      v0f[ds] = *reinterpret_cast<const bf16x8*>(sV + swz128(q32,    ds*32 + hi*16));
      v1f[ds] = *reinterpret_cast<const bf16x8*>(sV + swz128(32+q32, ds*32 + hi*16));
    }
    asm volatile("s_waitcnt lgkmcnt(0)" ::: "memory");
    __builtin_amdgcn_sched_barrier(0);
    if (ti + 1 < t1) { stageK(ti + 1); stageV(ti + 1); }

    f32x16 p0 = (f32x16)0.0f, p1 = (f32x16)0.0f;
    __builtin_amdgcn_s_setprio(1);
    #pragma unroll
    for (int ds=0; ds<4; ds++) {
      p0 = __builtin_amdgcn_mfma_f32_32x32x16_bf16(k0f[ds], qf[ds], p0, 0, 0, 0);
      p1 = __builtin_amdgcn_mfma_f32_32x32x16_bf16(k1f[ds], qf[ds], p1, 0, 0, 0);
    }
    __builtin_amdgcn_s_setprio(0);

    if (ti == qt) {
      #pragma unroll
      for (int r=0; r<16; r++) {
        int kg = ti*64 + (r&3) + 8*(r>>2) + 4*hi;
        if (kg      > qg) p0[r] = NEG_BIG;
        if (kg + 32 > qg) p1[r] = NEG_BIG;
      }
    }

    float mx[8];
    #pragma unroll
    for (int r=0;r<8;r++) mx[r] = fmaxf(fmaxf(p0[r],p0[r+8]), fmaxf(p1[r],p1[r+8]));
    #pragma unroll
    for (int st=4; st>0; st>>=1)
      #pragma unroll
      for (int r=0;r<st;r++) mx[r] = fmaxf(mx[r], mx[r+st]);
    float mt = fmaxf(mx[0], __shfl_xor(mx[0], 32, 64));

    if (!__all(mt <= mrun + 8.0f)) {
      float mnew  = fmaxf(mrun, mt);
      float alpha = exp2f(mrun - mnew);
      lrun *= alpha;
      O0 *= alpha; O1 *= alpha;
      mrun = mnew;
    }
    #pragma unroll
    for (int r=0; r<16; r++) {
      p0[r] = exp2f(p0[r] - mrun);
      p1[r] = exp2f(p1[r] - mrun);
    }
    float sx[8];
    #pragma unroll
    for (int r=0;r<8;r++) sx[r] = (p0[r]+p0[r+8]) + (p1[r]+p1[r+8]);
    #pragma unroll
    for (int st=4; st>0; st>>=1)
      #pragma unroll
      for (int r=0;r<st;r++) sx[r] += sx[r+st];
    lrun += sx[0] + __shfl_xor(sx[0], 32, 64);

    u32 pk0[8], pk1[8];
    #pragma unroll
    for (int i2=0; i2<8; i2++) {
      pk0[i2] = cvtpk_bf16(p0[2*i2], p0[2*i2+1]);
      pk1[i2] = cvtpk_bf16(p1[2*i2], p1[2*i2+1]);
    }
    plswap(pk0[0], pk0[2]); plswap(pk0[1], pk0[3]);
    plswap(pk0[4], pk0[6]); plswap(pk0[5], pk0[7]);
    plswap(pk1[0], pk1[2]); plswap(pk1[1], pk1[3]);
    plswap(pk1[4], pk1[6]); plswap(pk1[5], pk1[7]);

    bf16x8 pa[4];
    pa[0] = __builtin_bit_cast(bf16x8, (u32x4v){pk0[0],pk0[1],pk0[2],pk0[3]});
    pa[1] = __builtin_bit_cast(bf16x8, (u32x4v){pk0[4],pk0[5],pk0[6],pk0[7]});
    pa[2] = __builtin_bit_cast(bf16x8, (u32x4v){pk1[0],pk1[1],pk1[2],pk1[3]});
    pa[3] = __builtin_bit_cast(bf16x8, (u32x4v){pk1[4],pk1[5],pk1[6],pk1[7]});

    __builtin_amdgcn_s_setprio(1);
    #pragma unroll
    for (int ks=0; ks<4; ks++) {
      O0 = __builtin_amdgcn_mfma_f32_32x32x16_bf16(v0f[ks], pa[ks], O0, 0, 0, 0);
      O1 = __builtin_amdgcn_mfma_f32_32x32x16_bf16(v1f[ks], pa[ks], O1, 0, 0, 0);
    }
    __builtin_amdgcn_s_setprio(0);

    if (ti + 1 < t1) {
      asm volatile("s_waitcnt vmcnt(0)" ::: "memory");
      __builtin_amdgcn_sched_barrier(0);
    }
  }

  bf16_t* prow = pO + ((size_t)slot*2048 + q32*64);
  #pragma unroll
  for (int rg=0; rg<4; rg++) {
    int d0 = 8*rg + 4*hi;
    u32 a0 = cvtpk_bf16(O0[4*rg],   O0[4*rg+1]);
    u32 a1 = cvtpk_bf16(O0[4*rg+2], O0[4*rg+3]);
    *reinterpret_cast<u32x2v*>(prow + d0) = (u32x2v){a0, a1};
    u32 b0 = cvtpk_bf16(O1[4*rg],   O1[4*rg+1]);
    u32 b1 = cvtpk_bf16(O1[4*rg+2], O1[4*rg+3]);
    *reinterpret_cast<u32x2v*>(prow + 32 + d0) = (u32x2v){b0, b1};
  }
  if (hi == 0)
    pML[slot*32 + q32] = make_float2(mrun, lrun);
}

// ---------------- combine partials -> Of ----------------
__global__ __launch_bounds__(128) void combine(const bf16_t* __restrict__ pO,
                                               const float2* __restrict__ pML,
                                               bf16_t* __restrict__ Of) {
  int qw = blockIdx.x, bh = blockIdx.y;
  int b = bh >> 4, h = bh & 15;
  int t = threadIdx.x;
  int q = t >> 2, d0 = (t & 3) * 16;
  bf16x8 r0, r1;
  if (qw < 32) {
    int slot = bh*96 + qw;
    float2 ml = pML[slot*32 + q];
    float inv = 1.0f / ml.y;
    const bf16x8* src = reinterpret_cast<const bf16x8*>(pO + (size_t)slot*2048 + q*64 + d0);
    bf16x8 o0 = src[0], o1 = src[1];
    #pragma unroll
    for (int i=0;i<8;i++) {
      r0[i] = (bf16_t)((float)o0[i]*inv);
      r1[i] = (bf16_t)((float)o1[i]*inv);
    }
  } else {
    int s0 = bh*96 + 32 + (qw-32)*2;
    float2 mlA = pML[s0*32 + q];
    float2 mlB = pML[(s0+1)*32 + q];
    float m  = fmaxf(mlA.x, mlB.x);
    float a0 = exp2f(mlA.x - m), a1 = exp2f(mlB.x - m);
    float inv = 1.0f / (a0*mlA.y + a1*mlB.y);
    a0 *= inv; a1 *= inv;
    const bf16x8* sA = reinterpret_cast<const bf16x8*>(pO + (size_t)s0*2048 + q*64 + d0);
    const bf16x8* sB = reinterpret_cast<const bf16x8*>(pO + (size_t)(s0+1)*2048 + q*64 + d0);
    bf16x8 oa0 = sA[0], oa1 = sA[1], ob0 = sB[0], ob1 = sB[1];
    #pragma unroll
    for (int i=0;i<8;i++) {
      r0[i] = (bf16_t)(a0*(float)oa0[i] + a1*(float)ob0[i]);
      r1[i] = (bf16_t)(a0*(float)oa1[i] + a1*(float)ob1[i]);
    }
  }
  bf16x8* dst = reinterpret_cast<bf16x8*>(Of + ((size_t)(b*SEQ) + qw*32 + q)*D_MODEL + h*64 + d0);
  dst[0] = r0; dst[1] = r1;
}

// ---------------- launch ----------------
// Workspace lifetimes:
//   [ 0,  8) MB xb   (phases 1-2)  -> pO head  (attn/combine)
//   [ 8, 14) MB wqkv (phases 1-2)  -> pO tail (to 12.6MB) + pML (at 13MB)
//   [14, 16) MB wob  (all phases)
//   [16, 40) MB QKV  (gemm->attn)
//   [40, 48) MB Vtb  (gemm->attn)  -> Of (combine->out-gemm)
extern "C" void kernel_launch(void* const* d_in, const int* in_sizes, int n_in,
                              void* d_out, int out_size, void* d_ws, size_t ws_size,
                              hipStream_t stream) {
  const float* x   = (const float*)d_in[0];
  const int*   pos = (const int*)  d_in[1];
  const float* wq  = (const float*)d_in[2];
  const float* wk  = (const float*)d_in[3];
  const float* wv  = (const float*)d_in[4];
  const float* wo  = (const float*)d_in[5];
  float* out = (float*)d_out;

  char* ws = (char*)d_ws;
  bf16_t* xb   = (bf16_t*)(ws);
  bf16_t* wqkv = (bf16_t*)(ws + ( 8u<<20));
  bf16_t* wob  = (bf16_t*)(ws + (14u<<20));
  bf16_t* QKV  = (bf16_t*)(ws + (16u<<20));
  bf16_t* Vtb  = (bf16_t*)(ws + (40u<<20));
  bf16_t* pO   = (bf16_t*)(ws);                 // 32*96*2048*2B = 12.6 MB
  float2* pML  = (float2*)(ws + (13u<<20));     // 32*96*32*8B = 768 KB
  bf16_t* Of   = (bf16_t*)(ws + (40u<<20));     // overlays dead Vtb

  cvt_all<<<8*D_MODEL*D_MODEL/1024, 256, 0, stream>>>(x, wq, wk, wv, wo, xb, wqkv, wob);

  dim3 gqkv(NQKV/128, NTOK/256);    // (24, 16) = 384 blocks, 512 thr
  gemm_qkv<<<gqkv, 512, 0, stream>>>(xb, wqkv, QKV, Vtb, pos);

  dim3 gattn(32, 96);
  attn9<<<gattn, 64, 0, stream>>>(QKV, Vtb, pO, pML);

  dim3 gcomb(64, 32);
  combine<<<gcomb, 128, 0, stream>>>(pO, pML, Of);

  dim3 gout(D_MODEL/128, NTOK/128); // (8, 32) = 256 blocks
  gemm_out<<<gout, 256, 0, stream>>>(Of, wob, out, NTOK, D_MODEL, D_MODEL);
}